// Round 2
// baseline (500.916 us; speedup 1.0000x reference)
//
#include <hip/hip_runtime.h>
#include <hip/hip_bf16.h>

// Problem constants (from reference): N=50000 nodes, E=400000 edges,
// G=64 graphs, D_IN=200, D_HID=32, N_CLASS=2. All float arrays are fp32
// (reference dtype); edge_index/batch arrive as int32.
// Key restructure: segment_sum(x[src]) @ Wr == segment_sum((x@Wr)[src]),
// so we matmul first (200->32) and aggregate 32-wide rows (6.25x less traffic).
// CSR built on-device once per launch (graph is identical across layers).

#define D_IN 200
#define D_HID 32
#define N_GRAPHS 64
#define SCAN_THREADS 1024

// ---------------- CSR build ----------------
__global__ void count_edges(const int* __restrict__ dst, int* __restrict__ cnt, int E) {
    int e = blockIdx.x * blockDim.x + threadIdx.x;
    if (e < E) atomicAdd(&cnt[dst[e]], 1);
}

// Single-block scan: each thread sums a contiguous chunk, Hillis-Steele over
// 1024 partials in LDS, then writes exclusive prefixes (row_ptr + cursor copy).
__global__ void scan_kernel(const int* __restrict__ cnt, int* __restrict__ row_ptr,
                            int* __restrict__ cursor, int N) {
    __shared__ int sdata[SCAN_THREADS];
    int t = threadIdx.x;
    int chunk = (N + SCAN_THREADS - 1) / SCAN_THREADS;
    int s = t * chunk;
    int e = s + chunk; if (e > N) e = N; if (s > N) s = N;
    int sum = 0;
    for (int i = s; i < e; ++i) sum += cnt[i];
    sdata[t] = sum;
    __syncthreads();
    for (int off = 1; off < SCAN_THREADS; off <<= 1) {
        int v = (t >= off) ? sdata[t - off] : 0;
        __syncthreads();
        sdata[t] += v;
        __syncthreads();
    }
    int run = sdata[t] - sum;  // exclusive prefix of this thread's chunk
    for (int i = s; i < e; ++i) {
        row_ptr[i] = run;
        cursor[i]  = run;
        run += cnt[i];
    }
    if (t == SCAN_THREADS - 1) row_ptr[N] = sdata[SCAN_THREADS - 1];
}

__global__ void fill_csr(const int* __restrict__ src, const int* __restrict__ dst,
                         int* __restrict__ cursor, int* __restrict__ colIdx, int E) {
    int e = blockIdx.x * blockDim.x + threadIdx.x;
    if (e < E) {
        int p = atomicAdd(&cursor[dst[e]], 1);
        colIdx[p] = src[e];
    }
}

// ---------------- GEMM: X (N x K) @ [Wr | Wl] (K x 32 each) -> yr, yl (N x 32, fp32)
// Thread layout: col = tid&63 (0..31 -> Wr, 32..63 -> Wl), 4 nodes per thread.
// Each wave (64 lanes) shares one node's x element per k -> broadcast load;
// W row reads are coalesced 128B per half-wave.
template <int K>
__global__ void gemm64(const float* __restrict__ X,
                       const float* __restrict__ Wr,
                       const float* __restrict__ Wl,
                       float* __restrict__ yr, float* __restrict__ yl, int N) {
    int col = threadIdx.x & 63;
    int g   = threadIdx.x >> 6;            // wave id in block: 0..3
    int n0  = blockIdx.x * 16 + g * 4;     // first of 4 nodes for this thread
    if (n0 >= N) return;
    const float* W = (col < 32) ? Wr : Wl;
    int c = col & 31;

    int n[4];
#pragma unroll
    for (int i = 0; i < 4; ++i) { int v = n0 + i; n[i] = v < N ? v : N - 1; }

    float acc[4] = {0.f, 0.f, 0.f, 0.f};
    for (int k = 0; k < K; ++k) {
        float w = W[k * 32 + c];
#pragma unroll
        for (int i = 0; i < 4; ++i)
            acc[i] += X[n[i] * K + k] * w;
    }
    float* Y = (col < 32) ? yr : yl;
#pragma unroll
    for (int i = 0; i < 4; ++i)
        if (n0 + i < N) Y[(n0 + i) * 32 + c] = acc[i];
}

// ---------------- aggregate (CSR pull) + bias + root term + ELU ----------------
// 32 lanes per node (one per feature); gather of yr[j] rows is a coalesced
// 128B read per edge; writes coalesced. No atomics.
__global__ void agg_combine(const float* __restrict__ yr, const float* __restrict__ yl,
                            const int* __restrict__ row_ptr, const int* __restrict__ colIdx,
                            const float* __restrict__ b,
                            float* __restrict__ hout, int N) {
    int f = threadIdx.x & 31;
    int node = blockIdx.x * 8 + (threadIdx.x >> 5);
    if (node >= N) return;
    int s = row_ptr[node], e = row_ptr[node + 1];
    float acc = 0.f;
    for (int p = s; p < e; ++p) {
        int j = colIdx[p];
        acc += yr[j * 32 + f];
    }
    float v = acc + b[f] + yl[node * 32 + f];
    hout[node * 32 + f] = (v > 0.f) ? v : expm1f(v);  // ELU(alpha=1)
}

// ---------------- global mean pool (batch is sorted) ----------------
__global__ void pool_kernel(const float* __restrict__ h, const int* __restrict__ batch,
                            float* __restrict__ pooled, int N) {
    int g = blockIdx.x;  // one block per graph
    // lower_bound(g), lower_bound(g+1) on sorted batch
    int lo = 0, hi = N;
    while (lo < hi) { int mid = (lo + hi) >> 1; if (batch[mid] < g) lo = mid + 1; else hi = mid; }
    int start = lo;
    hi = N;
    while (lo < hi) { int mid = (lo + hi) >> 1; if (batch[mid] < g + 1) lo = mid + 1; else hi = mid; }
    int end = lo;

    int f = threadIdx.x & 31, r = threadIdx.x >> 5;  // 8 row-groups x 32 feats
    float acc = 0.f;
    for (int i = start + r; i < end; i += 8) acc += h[i * 32 + f];
    __shared__ float red[8][32];
    red[r][f] = acc;
    __syncthreads();
    if (threadIdx.x < 32) {
        float s = 0.f;
#pragma unroll
        for (int r2 = 0; r2 < 8; ++r2) s += red[r2][f];
        float cntf = (float)(end - start);
        pooled[g * 32 + f] = s / fmaxf(cntf, 1.f);
    }
}

// ---------------- linear head + log_softmax (64x32 @ 32x2) ----------------
__global__ void head_kernel(const float* __restrict__ pooled,
                            const float* __restrict__ Wlin,
                            const float* __restrict__ blin,
                            float* __restrict__ out) {
    int g = threadIdx.x;
    if (g >= N_GRAPHS) return;
    float c0 = blin[0];
    float c1 = blin[1];
    for (int k = 0; k < 32; ++k) {
        float p = pooled[g * 32 + k];
        c0 += p * Wlin[k * 2 + 0];
        c1 += p * Wlin[k * 2 + 1];
    }
    float m = fmaxf(c0, c1);
    float lse = m + logf(expf(c0 - m) + expf(c1 - m));
    out[g * 2 + 0] = c0 - lse;
    out[g * 2 + 1] = c1 - lse;
}

extern "C" void kernel_launch(void* const* d_in, const int* in_sizes, int n_in,
                              void* d_out, int out_size, void* d_ws, size_t ws_size,
                              hipStream_t stream) {
    // inputs (setup_inputs order): x, edge_index, edge_attr, batch,
    // W1r, W1l, b1, W2r, W2l, b2, W3r, W3l, b3, Wlin, blin
    const float* x     = (const float*)d_in[0];
    const int*   eidx  = (const int*)d_in[1];
    const int*   batch = (const int*)d_in[3];
    const float* W1r = (const float*)d_in[4];
    const float* W1l = (const float*)d_in[5];
    const float* b1  = (const float*)d_in[6];
    const float* W2r = (const float*)d_in[7];
    const float* W2l = (const float*)d_in[8];
    const float* b2  = (const float*)d_in[9];
    const float* W3r = (const float*)d_in[10];
    const float* W3l = (const float*)d_in[11];
    const float* b3  = (const float*)d_in[12];
    const float* Wlin = (const float*)d_in[13];
    const float* blin = (const float*)d_in[14];
    float* out = (float*)d_out;

    const int N = in_sizes[0] / D_IN;  // 50000
    const int E = in_sizes[1] / 2;     // 400000
    const int* src = eidx;
    const int* dst = eidx + E;

    // workspace carve-out (256B aligned); ~22 MB total
    char* w = (char*)d_ws;
    auto alloc = [&](size_t bytes) -> void* {
        void* p = (void*)w;
        w += (bytes + 255) & ~(size_t)255;
        return p;
    };
    int*   cnt     = (int*)alloc((size_t)N * 4);
    int*   row_ptr = (int*)alloc((size_t)(N + 1) * 4);
    int*   cursor  = (int*)alloc((size_t)(N + 1) * 4);
    int*   colIdx  = (int*)alloc((size_t)E * 4);
    float* yr      = (float*)alloc((size_t)N * 32 * 4);
    float* yl      = (float*)alloc((size_t)N * 32 * 4);
    float* hA      = (float*)alloc((size_t)N * 32 * 4);
    float* pooled  = (float*)alloc((size_t)N_GRAPHS * 32 * 4);

    // --- CSR build (once per launch; graph shared by all 3 layers) ---
    hipMemsetAsync(cnt, 0, (size_t)N * 4, stream);
    int egrid = (E + 255) / 256;
    count_edges<<<egrid, 256, 0, stream>>>(dst, cnt, E);
    scan_kernel<<<1, SCAN_THREADS, 0, stream>>>(cnt, row_ptr, cursor, N);
    fill_csr<<<egrid, 256, 0, stream>>>(src, dst, cursor, colIdx, E);

    int ggrid = (N + 15) / 16;  // gemm blocks (16 nodes/block)
    int agrid = (N + 7) / 8;    // agg blocks (8 nodes/block)

    // --- layer 1 (K=200) ---
    gemm64<D_IN><<<ggrid, 256, 0, stream>>>(x, W1r, W1l, yr, yl, N);
    agg_combine<<<agrid, 256, 0, stream>>>(yr, yl, row_ptr, colIdx, b1, hA, N);
    // --- layer 2 (K=32); hA safe to overwrite after gemm consumed it (stream-ordered) ---
    gemm64<D_HID><<<ggrid, 256, 0, stream>>>(hA, W2r, W2l, yr, yl, N);
    agg_combine<<<agrid, 256, 0, stream>>>(yr, yl, row_ptr, colIdx, b2, hA, N);
    // --- layer 3 ---
    gemm64<D_HID><<<ggrid, 256, 0, stream>>>(hA, W3r, W3l, yr, yl, N);
    agg_combine<<<agrid, 256, 0, stream>>>(yr, yl, row_ptr, colIdx, b3, hA, N);

    // --- pool + head ---
    pool_kernel<<<N_GRAPHS, 256, 0, stream>>>(hA, batch, pooled, N);
    head_kernel<<<1, 64, 0, stream>>>(pooled, Wlin, blin, out);
}

// Round 3
// 313.970 us; speedup vs baseline: 1.5954x; 1.5954x over previous
//
#include <hip/hip_runtime.h>
#include <hip/hip_bf16.h>

// GCN: 3x GraphConv(sum-agg) + ELU, mean-pool, linear head, log_softmax.
// N=50000, E=400000, G=64, D_IN=200, D_HID=32. All float inputs fp32.
// Restructure: segment_sum(x[src]) @ Wr == segment_sum((x@Wr)[src]) -> matmul
// first (200->32), aggregate 32-wide rows via CSR pull (no float atomics).

#define D_IN 200
#define D_HID 32
#define N_GRAPHS 64

#define SCAN_TILE 2048   // elements per scan block (256 thr x 8)
#define SCAN_ITEMS 8

// ---------------- CSR build ----------------
__global__ void count_edges(const int* __restrict__ dst, int* __restrict__ cnt, int E) {
    int e = blockIdx.x * blockDim.x + threadIdx.x;
    if (e < E) atomicAdd(&cnt[dst[e]], 1);
}

// Pass 1: per-block sums of cnt tiles.
__global__ void scan_partial(const int* __restrict__ cnt, int* __restrict__ partial, int N) {
    __shared__ int sdata[256];
    int t = threadIdx.x;
    int base = blockIdx.x * SCAN_TILE + t * SCAN_ITEMS;
    int s = 0;
#pragma unroll
    for (int i = 0; i < SCAN_ITEMS; ++i) {
        int idx = base + i;
        if (idx < N) s += cnt[idx];
    }
    sdata[t] = s;
    __syncthreads();
    for (int off = 128; off > 0; off >>= 1) {
        if (t < off) sdata[t] += sdata[t + off];
        __syncthreads();
    }
    if (t == 0) partial[blockIdx.x] = sdata[0];
}

// Pass 2: exclusive scan of the (~25) block partials. Tiny; serial is fine.
__global__ void scan_offsets(int* __restrict__ partial, int numBlocks) {
    if (threadIdx.x == 0) {
        int run = 0;
        for (int i = 0; i < numBlocks; ++i) { int v = partial[i]; partial[i] = run; run += v; }
    }
}

// Pass 3: block-local exclusive scan + global offset -> row_ptr & cursor.
__global__ void scan_final(const int* __restrict__ cnt, const int* __restrict__ partial,
                           int* __restrict__ row_ptr, int* __restrict__ cursor, int N) {
    __shared__ int sdata[256];
    int t = threadIdx.x;
    int base = blockIdx.x * SCAN_TILE + t * SCAN_ITEMS;
    int vals[SCAN_ITEMS];
    int s = 0;
#pragma unroll
    for (int i = 0; i < SCAN_ITEMS; ++i) {
        int idx = base + i;
        vals[i] = (idx < N) ? cnt[idx] : 0;
        s += vals[i];
    }
    sdata[t] = s;
    __syncthreads();
    int sum = s;
    for (int off = 1; off < 256; off <<= 1) {
        int v = (t >= off) ? sdata[t - off] : 0;
        __syncthreads();
        sdata[t] += v;
        __syncthreads();
    }
    int run = partial[blockIdx.x] + sdata[t] - sum;  // exclusive prefix
#pragma unroll
    for (int i = 0; i < SCAN_ITEMS; ++i) {
        int idx = base + i;
        if (idx < N) { row_ptr[idx] = run; cursor[idx] = run; run += vals[i]; }
    }
    if (blockIdx.x == gridDim.x - 1 && t == 255) row_ptr[N] = partial[blockIdx.x] + sdata[255];
}

__global__ void fill_csr(const int* __restrict__ src, const int* __restrict__ dst,
                         int* __restrict__ cursor, int* __restrict__ colIdx, int E) {
    int e = blockIdx.x * blockDim.x + threadIdx.x;
    if (e < E) {
        int p = atomicAdd(&cursor[dst[e]], 1);
        colIdx[p] = src[e];
    }
}

// ---------------- GEMM: X (N x K) @ [Wr | Wl] (K x 32 each) -> yr, yl ----------------
// 32 nodes/block. Stage X rows into LDS via coalesced float4 copy (the 32 rows
// are one contiguous span). Compute: col=tid&63 (r/l), wave g owns 8 nodes;
// per k4: 4 L1-cached W loads + 8 broadcast ds_read_b128 + 32 FMA.
template <int K>
__global__ __launch_bounds__(256) void gemm_lds(const float* __restrict__ X,
                                                const float* __restrict__ Wr,
                                                const float* __restrict__ Wl,
                                                float* __restrict__ yr, float* __restrict__ yl,
                                                int N) {
    constexpr int K4 = K / 4;
    __shared__ float4 xs[32 * K4];
    int t = threadIdx.x;
    long base = (long)blockIdx.x * 32;
    const float4* X4 = (const float4*)X;
    for (int i = t; i < 32 * K4; i += 256) {
        int node = (int)base + i / K4;
        int k4 = i % K4;
        if (node < N) xs[i] = X4[(long)node * K4 + k4];
        else          xs[i] = make_float4(0.f, 0.f, 0.f, 0.f);
    }
    __syncthreads();

    int col = t & 63, c = col & 31;
    const float* W = (col < 32) ? Wr : Wl;
    int nb = (t >> 6) * 8;  // first of 8 nodes for this wave
    float acc[8] = {0.f, 0.f, 0.f, 0.f, 0.f, 0.f, 0.f, 0.f};
    for (int k4 = 0; k4 < K4; ++k4) {
        float w0 = W[(k4 * 4 + 0) * 32 + c];
        float w1 = W[(k4 * 4 + 1) * 32 + c];
        float w2 = W[(k4 * 4 + 2) * 32 + c];
        float w3 = W[(k4 * 4 + 3) * 32 + c];
#pragma unroll
        for (int i = 0; i < 8; ++i) {
            float4 xv = xs[(nb + i) * K4 + k4];
            acc[i] += xv.x * w0;
            acc[i] += xv.y * w1;
            acc[i] += xv.z * w2;
            acc[i] += xv.w * w3;
        }
    }
    float* Y = (col < 32) ? yr : yl;
#pragma unroll
    for (int i = 0; i < 8; ++i) {
        long node = base + nb + i;
        if (node < N) Y[node * 32 + c] = acc[i];
    }
}

// ---------------- aggregate (CSR pull) + bias + root + ELU, float4-wide ----------------
// 8 lanes per node (float4 each): one b128 gather inst serves 8 node-chains
// (1 KB); 8 independent latency chains per wave.
__global__ __launch_bounds__(256) void agg_combine(const float4* __restrict__ yr4,
                                                   const float4* __restrict__ yl4,
                                                   const int* __restrict__ row_ptr,
                                                   const int* __restrict__ colIdx,
                                                   const float* __restrict__ b,
                                                   float4* __restrict__ hout4, int N) {
    int t = threadIdx.x;
    int f4 = t & 7;
    int node = blockIdx.x * 32 + (t >> 3);
    if (node >= N) return;
    int s = row_ptr[node], e = row_ptr[node + 1];
    float ax = 0.f, ay = 0.f, az = 0.f, aw = 0.f;
    for (int p = s; p < e; ++p) {
        int j = colIdx[p];
        float4 v = yr4[(long)j * 8 + f4];
        ax += v.x; ay += v.y; az += v.z; aw += v.w;
    }
    float4 bb = ((const float4*)b)[f4];
    float4 rv = yl4[(long)node * 8 + f4];
    float vx = ax + bb.x + rv.x;
    float vy = ay + bb.y + rv.y;
    float vz = az + bb.z + rv.z;
    float vw = aw + bb.w + rv.w;
    float4 o;
    o.x = (vx > 0.f) ? vx : expm1f(vx);
    o.y = (vy > 0.f) ? vy : expm1f(vy);
    o.z = (vz > 0.f) ? vz : expm1f(vz);
    o.w = (vw > 0.f) ? vw : expm1f(vw);
    hout4[(long)node * 8 + f4] = o;
}

// ---------------- global mean pool (batch is sorted) ----------------
__global__ void pool_kernel(const float* __restrict__ h, const int* __restrict__ batch,
                            float* __restrict__ pooled, int N) {
    int g = blockIdx.x;
    int lo = 0, hi = N;
    while (lo < hi) { int mid = (lo + hi) >> 1; if (batch[mid] < g) lo = mid + 1; else hi = mid; }
    int start = lo;
    hi = N;
    while (lo < hi) { int mid = (lo + hi) >> 1; if (batch[mid] < g + 1) lo = mid + 1; else hi = mid; }
    int end = lo;

    int f = threadIdx.x & 31, r = threadIdx.x >> 5;
    float acc = 0.f;
    for (int i = start + r; i < end; i += 8) acc += h[i * 32 + f];
    __shared__ float red[8][32];
    red[r][f] = acc;
    __syncthreads();
    if (threadIdx.x < 32) {
        float s = 0.f;
#pragma unroll
        for (int r2 = 0; r2 < 8; ++r2) s += red[r2][f];
        float cntf = (float)(end - start);
        pooled[g * 32 + f] = s / fmaxf(cntf, 1.f);
    }
}

// ---------------- linear head + log_softmax ----------------
__global__ void head_kernel(const float* __restrict__ pooled,
                            const float* __restrict__ Wlin,
                            const float* __restrict__ blin,
                            float* __restrict__ out) {
    int g = threadIdx.x;
    if (g >= N_GRAPHS) return;
    float c0 = blin[0];
    float c1 = blin[1];
    for (int k = 0; k < 32; ++k) {
        float p = pooled[g * 32 + k];
        c0 += p * Wlin[k * 2 + 0];
        c1 += p * Wlin[k * 2 + 1];
    }
    float m = fmaxf(c0, c1);
    float lse = m + logf(expf(c0 - m) + expf(c1 - m));
    out[g * 2 + 0] = c0 - lse;
    out[g * 2 + 1] = c1 - lse;
}

extern "C" void kernel_launch(void* const* d_in, const int* in_sizes, int n_in,
                              void* d_out, int out_size, void* d_ws, size_t ws_size,
                              hipStream_t stream) {
    const float* x     = (const float*)d_in[0];
    const int*   eidx  = (const int*)d_in[1];
    const int*   batch = (const int*)d_in[3];
    const float* W1r = (const float*)d_in[4];
    const float* W1l = (const float*)d_in[5];
    const float* b1  = (const float*)d_in[6];
    const float* W2r = (const float*)d_in[7];
    const float* W2l = (const float*)d_in[8];
    const float* b2  = (const float*)d_in[9];
    const float* W3r = (const float*)d_in[10];
    const float* W3l = (const float*)d_in[11];
    const float* b3  = (const float*)d_in[12];
    const float* Wlin = (const float*)d_in[13];
    const float* blin = (const float*)d_in[14];
    float* out = (float*)d_out;

    const int N = in_sizes[0] / D_IN;  // 50000
    const int E = in_sizes[1] / 2;     // 400000
    const int* src = eidx;
    const int* dst = eidx + E;

    char* w = (char*)d_ws;
    auto alloc = [&](size_t bytes) -> void* {
        void* p = (void*)w;
        w += (bytes + 255) & ~(size_t)255;
        return p;
    };
    int*   cnt     = (int*)alloc((size_t)N * 4);
    int*   row_ptr = (int*)alloc((size_t)(N + 1) * 4);
    int*   cursor  = (int*)alloc((size_t)(N + 1) * 4);
    int*   colIdx  = (int*)alloc((size_t)E * 4);
    int*   partial = (int*)alloc((size_t)256 * 4);
    float* yr      = (float*)alloc((size_t)N * 32 * 4);
    float* yl      = (float*)alloc((size_t)N * 32 * 4);
    float* hA      = (float*)alloc((size_t)N * 32 * 4);
    float* pooled  = (float*)alloc((size_t)N_GRAPHS * 32 * 4);

    // --- CSR build ---
    hipMemsetAsync(cnt, 0, (size_t)N * 4, stream);
    int egrid = (E + 255) / 256;
    int sgrid = (N + SCAN_TILE - 1) / SCAN_TILE;  // 25
    count_edges<<<egrid, 256, 0, stream>>>(dst, cnt, E);
    scan_partial<<<sgrid, 256, 0, stream>>>(cnt, partial, N);
    scan_offsets<<<1, 64, 0, stream>>>(partial, sgrid);
    scan_final<<<sgrid, 256, 0, stream>>>(cnt, partial, row_ptr, cursor, N);
    fill_csr<<<egrid, 256, 0, stream>>>(src, dst, cursor, colIdx, E);

    int ggrid = (N + 31) / 32;  // 1563

    // --- layer 1 (K=200) ---
    gemm_lds<D_IN><<<ggrid, 256, 0, stream>>>(x, W1r, W1l, yr, yl, N);
    agg_combine<<<ggrid, 256, 0, stream>>>((const float4*)yr, (const float4*)yl,
                                           row_ptr, colIdx, b1, (float4*)hA, N);
    // --- layer 2 (K=32) ---
    gemm_lds<D_HID><<<ggrid, 256, 0, stream>>>(hA, W2r, W2l, yr, yl, N);
    agg_combine<<<ggrid, 256, 0, stream>>>((const float4*)yr, (const float4*)yl,
                                           row_ptr, colIdx, b2, (float4*)hA, N);
    // --- layer 3 ---
    gemm_lds<D_HID><<<ggrid, 256, 0, stream>>>(hA, W3r, W3l, yr, yl, N);
    agg_combine<<<ggrid, 256, 0, stream>>>((const float4*)yr, (const float4*)yl,
                                           row_ptr, colIdx, b3, (float4*)hA, N);

    // --- pool + head ---
    pool_kernel<<<N_GRAPHS, 256, 0, stream>>>(hA, batch, pooled, N);
    head_kernel<<<1, 64, 0, stream>>>(pooled, Wlin, blin, out);
}